// Round 4
// baseline (366.856 us; speedup 1.0000x reference)
//
#include <hip/hip_runtime.h>

#define NBATCH 128
#define IMG_H 512
#define IMG_W 512
#define RADIUS 45          // 3 stages * 15 iterations
#define AW 92              // active window (offsets -45..+46)
#define PW 94              // padded (+1 zero ring each side)
#define PCELLS (PW * PW)
#define NITER 15
#define NSTAGES 3
#define NT 1024

__global__ __launch_bounds__(NT)
void reach_kernel(const float* __restrict__ floor_p,
                  const float* __restrict__ key_loc,
                  const float* __restrict__ locked,
                  const int*   __restrict__ start_c,
                  const int*   __restrict__ goal_c,
                  const float* __restrict__ key_gate_p,
                  float* __restrict__ out)
{
    extern __shared__ float lds[];
    float* Rb[2];
    Rb[0] = lds;
    Rb[1] = lds + PCELLS;
    float* walk = lds + 2 * PCELLS;
    __shared__ float red[NT / 64];
    __shared__ float bcast;

    const int b   = blockIdx.x;
    const int tid = threadIdx.x;
    const float key_gate = key_gate_p[0];
    const int sr = start_c[b * 2 + 0];
    const int sc = start_c[b * 2 + 1];
    const int r0 = sr - RADIUS;   // global row of active index 0
    const int c0 = sc - RADIUS;

    const float* fp_b = floor_p + (size_t)b * IMG_H * IMG_W;
    const float* kl_b = key_loc + (size_t)b * IMG_H * IMG_W;
    const float* ld_b = locked  + (size_t)b * IMG_H * IMG_W;

    // zero all LDS tiles (padding ring included)
    for (int i = tid; i < PCELLS; i += NT) {
        Rb[0][i] = 0.0f;
        Rb[1][i] = 0.0f;
        walk[i]  = 0.0f;
    }
    __syncthreads();
    if (tid == 0) {
        // seed reachability at the start cell (active coord (45,45))
        Rb[0][(1 + RADIUS) * PW + (1 + RADIUS)] = 1.0f;
    }
    // ordered before any read by the __syncthreads at end of walk build

    int   cur = 0;
    float kc  = 0.0f;
    int   t   = 0;    // global iteration counter (support radius)

    for (int stage = 0; stage < NSTAGES; ++stage) {
        // door_pass = sigmoid(key_gate * (kc - 1))
        const float dp = 1.0f / (1.0f + expf(-key_gate * (kc - 1.0f)));

        // build walk tile for this stage: walk = floor * (1 - locked + locked*dp)
        for (int i = tid; i < AW * AW; i += NT) {
            const int ri = i / AW;
            const int ci = i - ri * AW;
            const int gr = r0 + ri;
            const int gc = c0 + ci;
            float w = 0.0f;
            if ((unsigned)gr < IMG_H && (unsigned)gc < IMG_W) {
                const float f = fp_b[gr * IMG_W + gc];
                const float l = ld_b[gr * IMG_W + gc];
                w = f * (1.0f - l + l * dp);
            }
            walk[(ri + 1) * PW + (ci + 1)] = w;
        }
        __syncthreads();

        // 15 Jacobi iterations on the growing box
        for (int it = 0; it < NITER; ++it) {
            ++t;
            const int h    = (t < RADIUS) ? t : RADIUS;
            const int s    = 2 * h + 1;
            const int base = 1 + RADIUS - h;      // padded coord of box start
            const float* __restrict__ Ro = Rb[cur];
            float* __restrict__       Rn = Rb[cur ^ 1];
            const int cells = s * s;
            for (int i = tid; i < cells; i += NT) {
                const int ri  = i / s;
                const int ci  = i - ri * s;
                const int idx = (base + ri) * PW + (base + ci);
                const float center = Ro[idx];
                const float nb = Ro[idx - PW] + Ro[idx + PW]
                               + Ro[idx - 1]  + Ro[idx + 1];
                float v = center + 0.25f * nb * walk[idx];
                v = v < 0.0f ? 0.0f : (v > 1.0f ? 1.0f : v);
                Rn[idx] = v;
            }
            cur ^= 1;
            __syncthreads();
        }

        // keys_collected += sum(R * key_locations) over the current box
        {
            const int h     = (t < RADIUS) ? t : RADIUS;
            const int s     = 2 * h + 1;
            const int base0 = RADIUS - h;         // active coord of box start
            const float* __restrict__ Rc = Rb[cur];
            float lsum = 0.0f;
            const int cells = s * s;
            for (int i = tid; i < cells; i += NT) {
                const int ri = i / s;
                const int ci = i - ri * s;
                const int ar = base0 + ri;
                const int ac = base0 + ci;
                const int gr = r0 + ar;
                const int gc = c0 + ac;
                if ((unsigned)gr < IMG_H && (unsigned)gc < IMG_W) {
                    lsum += Rc[(ar + 1) * PW + (ac + 1)] * kl_b[gr * IMG_W + gc];
                }
            }
            for (int off = 32; off > 0; off >>= 1)
                lsum += __shfl_down(lsum, off, 64);
            if ((tid & 63) == 0) red[tid >> 6] = lsum;
            __syncthreads();
            if (tid == 0) {
                float tot = 0.0f;
                for (int w = 0; w < NT / 64; ++w) tot += red[w];
                bcast = tot;
            }
            __syncthreads();
            kc += bcast;
            __syncthreads();   // protect red/bcast before next stage reuses them
        }
    }

    if (tid == 0) {
        int gr = goal_c[b * 2 + 0];
        int gc = goal_c[b * 2 + 1];
        gr = gr < 0 ? 0 : (gr > IMG_H - 1 ? IMG_H - 1 : gr);
        gc = gc < 0 ? 0 : (gc > IMG_W - 1 ? IMG_W - 1 : gc);
        const int li = gr - r0;
        const int lj = gc - c0;
        float v = 0.0f;
        if (li >= 0 && li < AW && lj >= 0 && lj < AW)
            v = Rb[cur][(li + 1) * PW + (lj + 1)];
        out[b] = v;
    }
}

extern "C" void kernel_launch(void* const* d_in, const int* in_sizes, int n_in,
                              void* d_out, int out_size, void* d_ws, size_t ws_size,
                              hipStream_t stream) {
    const float* floor_p = (const float*)d_in[0];
    const float* key_loc = (const float*)d_in[1];
    const float* locked  = (const float*)d_in[2];
    const int*   start_c = (const int*)d_in[3];
    const int*   goal_c  = (const int*)d_in[4];
    const float* key_g   = (const float*)d_in[5];
    float* out = (float*)d_out;

    const size_t shmem = (size_t)(3 * PCELLS) * sizeof(float);  // ~106 KB
    // Host-side config call (not a stream op) — safe under graph capture;
    // idempotent, so set it on every call. Check the result so a failure is
    // loud (launch error) instead of silent garbage.
    (void)hipFuncSetAttribute((const void*)reach_kernel,
                              hipFuncAttributeMaxDynamicSharedMemorySize,
                              (int)shmem);

    reach_kernel<<<NBATCH, NT, shmem, stream>>>(
        floor_p, key_loc, locked, start_c, goal_c, key_g, out);
}